// Round 5
// baseline (76.446 us; speedup 1.0000x reference)
//
#include <hip/hip_runtime.h>

#define TGS_D 128
#define TGS_E 20
#define TGS_K 10
#define TGS_F1 276               // 2D+E
#define LDA1 296                 // f16 stride for A1 panel (16B-aligned rows)
#define LDA2 264                 // f16 stride for A2 panel
#define RPB 16                   // rows per block (one M-tile)

typedef _Float16 f16;
typedef _Float16 f16x4 __attribute__((ext_vector_type(4)));
typedef _Float16 f16x8 __attribute__((ext_vector_type(8)));
typedef float    f32x4 __attribute__((ext_vector_type(4)));

// ---------------- merged setup: pack W1, pack W2, tvec ----------------
// blocks 0..143: PW1[((layer*8+ntile)*9+kk)*64+lane] = W1[layer][kk*32+(lane>>4)*8+j][ntile*16+(lane&15)]
// blocks 144..271: PW2 (A2 k: [0:128)=src -> W2 row k ; [128:256) -> W2 row k+128)
// blocks 272..273: tvec[l][d] = B2[l][d] + sum_j cos(tb[j]) * W2[l][128+j][d]
__global__ __launch_bounds__(128)
void tgs_setup(const float* __restrict__ W1, const float* __restrict__ W2,
               const float* __restrict__ tb, const float* __restrict__ B2,
               f16x8* __restrict__ PW1, f16x8* __restrict__ PW2,
               float* __restrict__ tvec) {
    const int b = blockIdx.x, tid = threadIdx.x;
    if (b < 144) {
        if (tid < 64) {
            const int layer = b / 72, rem = b % 72, ntile = rem / 9, kk = rem % 9;
            const int colg = ntile * 16 + (tid & 15);
            const int kbase = kk * 32 + (tid >> 4) * 8;
            f16x8 v;
            #pragma unroll
            for (int j = 0; j < 8; ++j) {
                const int k = kbase + j;
                v[j] = (k < TGS_F1) ? (f16)W1[(layer * TGS_F1 + k) * TGS_D + colg] : (f16)0.f;
            }
            PW1[b * 64 + tid] = v;
        }
    } else if (b < 272) {
        if (tid < 64) {
            const int bb = b - 144;
            const int layer = bb / 64, rem = bb % 64, ntile = rem / 8, kk = rem % 8;
            const int colg = ntile * 16 + (tid & 15);
            const int kbase = kk * 32 + (tid >> 4) * 8;
            f16x8 v;
            #pragma unroll
            for (int j = 0; j < 8; ++j) {
                const int k = kbase + j;
                const int w2row = (k < TGS_D) ? k : (k + TGS_D);
                v[j] = (f16)W2[(layer * 3 * TGS_D + w2row) * TGS_D + colg];
            }
            PW2[bb * 64 + tid] = v;
        }
    } else {
        const int l = b - 272, d = tid;
        const float* w = W2 + (l * 3 * TGS_D + TGS_D) * TGS_D;
        float acc = B2[l * TGS_D + d];
        for (int j = 0; j < TGS_D; ++j)
            acc = fmaf(__cosf(tb[j]), w[j * TGS_D + d], acc);
        tvec[l * TGS_D + d] = acc;
    }
}

// ---------------- fused per-level kernel: gather+sum -> MFMA GEMM1 -> MFMA GEMM2 ----
// 512 threads = 8 waves; each wave owns one 16-wide N-tile (wid).
template<int LEVEL, typename OutT>
__global__ __launch_bounds__(512, 4)
void tgs_agg_kernel(
    const float* __restrict__ NF, const float* __restrict__ EF,
    const int* __restrict__ src_ids, const float* __restrict__ ts_arr,
    const int* __restrict__ nbr_idx,   // LEVEL1 only
    const int* __restrict__ eidx, const float* __restrict__ etime,
    const f16* __restrict__ emb_in,    // LEVEL2 only (f16)
    const float* __restrict__ tw, const float* __restrict__ tb,
    const f16x8* __restrict__ PW1, const float* __restrict__ B1,
    const f16x8* __restrict__ PW2, const float* __restrict__ tvec,
    OutT* __restrict__ out)
{
    __shared__ f16 snf[RPB][LDA1];     // A1: [nodesum 0:128 | timesum 128:256 | edgesum 256:276 | zeroed pad 276:288]
    __shared__ f16 sf2[RPB][LDA2];     // A2: [src 0:128 | relusum 128:256 | pad]
    __shared__ int   s_nbr[RPB * TGS_K];
    __shared__ int   s_eid[RPB * TGS_K];
    __shared__ float s_et [RPB * TGS_K];
    __shared__ float s_ts [RPB];

    const int tid = threadIdx.x;
    const int lane = tid & 63;
    const int wid  = tid >> 6;         // wave id = N-tile
    const int base_row = blockIdx.x * RPB;

    // ---- prefetch GEMM1 B-fragments NOW; consumed after the phase-0 barrier,
    //      so their ~200cy L2 latency hides under the entire gather phase ----
    f16x8 bf1[9];
    #pragma unroll
    for (int kk = 0; kk < 9; ++kk)
        bf1[kk] = PW1[(wid * 9 + kk) * 64 + lane];

    // ---- stage indices / times ----
    if (tid < RPB * TGS_K) {
        if (LEVEL == 1) s_nbr[tid] = nbr_idx[base_row * TGS_K + tid];
        s_eid[tid] = eidx[base_row * TGS_K + tid];
        s_et [tid] = etime[base_row * TGS_K + tid];
    }
    if (tid < RPB)
        s_ts[tid] = (LEVEL == 1) ? ts_arr[(base_row + tid) / TGS_K] : ts_arr[base_row + tid];
    __syncthreads();

    // ---- phase 0: gather + K-sum (fp32), write f16 panels; one row per 32-lane group ----
    {
        const int sub = tid & 31;      // float4 slot within 128
        const int r   = tid >> 5;      // 0..15
        const int row = base_row + r;
        const float4 wv = ((const float4*)tw)[sub];
        const float4 bv = ((const float4*)tb)[sub];

        // neighbor-embedding K-sum
        float4 a = make_float4(0.f, 0.f, 0.f, 0.f);
        if (LEVEL == 1) {
            #pragma unroll
            for (int k = 0; k < TGS_K; ++k) {
                const int nb = s_nbr[r * TGS_K + k];
                const float4 v = ((const float4*)(NF + nb * TGS_D))[sub];
                a.x += v.x; a.y += v.y; a.z += v.z; a.w += v.w;
            }
        } else {
            #pragma unroll
            for (int k = 0; k < TGS_K; ++k) {
                const f16x4 v = ((const f16x4*)(emb_in + (row * TGS_K + k) * TGS_D))[sub];
                a.x += (float)v[0]; a.y += (float)v[1]; a.z += (float)v[2]; a.w += (float)v[3];
            }
        }
        *(f16x4*)&snf[r][sub * 4] = f16x4{(f16)a.x, (f16)a.y, (f16)a.z, (f16)a.w};

        // source features
        const int sid = src_ids[row];
        const float4 s = ((const float4*)(NF + sid * TGS_D))[sub];
        *(f16x4*)&sf2[r][sub * 4] = f16x4{(f16)s.x, (f16)s.y, (f16)s.z, (f16)s.w};

        // edge-time-encoding K-sum: cos((ts-et)*w + b)
        const float ts = s_ts[r];
        float4 st = make_float4(0.f, 0.f, 0.f, 0.f);
        #pragma unroll
        for (int k = 0; k < TGS_K; ++k) {
            const float dt = ts - s_et[r * TGS_K + k];
            st.x += __cosf(fmaf(dt, wv.x, bv.x));
            st.y += __cosf(fmaf(dt, wv.y, bv.y));
            st.z += __cosf(fmaf(dt, wv.z, bv.z));
            st.w += __cosf(fmaf(dt, wv.w, bv.w));
        }
        *(f16x4*)&snf[r][TGS_D + sub * 4] = f16x4{(f16)st.x, (f16)st.y, (f16)st.z, (f16)st.w};

        // edge-feature K-sum (20 = 5 float4 slots); lanes 5..7 zero the pad [276,288)
        // (GEMM1's kk=8 step reads it -- stale NaN bits would poison the MFMA row)
        if (sub < TGS_E / 4) {
            float4 e = make_float4(0.f, 0.f, 0.f, 0.f);
            #pragma unroll
            for (int k = 0; k < TGS_K; ++k) {
                const int eb = s_eid[r * TGS_K + k];
                const float4 v = ((const float4*)(EF + eb * TGS_E))[sub];
                e.x += v.x; e.y += v.y; e.z += v.z; e.w += v.w;
            }
            *(f16x4*)&snf[r][2 * TGS_D + sub * 4] = f16x4{(f16)e.x, (f16)e.y, (f16)e.z, (f16)e.w};
        } else if (sub < 8) {
            *(f16x4*)&snf[r][2 * TGS_D + sub * 4] =
                f16x4{(f16)0.f, (f16)0.f, (f16)0.f, (f16)0.f};
        }
    }
    __syncthreads();

    const int ccol = lane & 15;        // C/D col; also A row for A-frag reads
    const int row0 = (lane >> 4) * 4;  // C/D row base

    // ---- GEMM1: h = relu(A1 @ W1 + 10*b1) -> sf2 relusum panel (f16) ----
    f16x8 bf2[8];
    {
        f32x4 acc = {0.f, 0.f, 0.f, 0.f};
        const f16* abase = &snf[ccol][(lane >> 4) * 8];
        #pragma unroll
        for (int kk = 0; kk < 9; ++kk) {
            const f16x8 af = *(const f16x8*)(abase + kk * 32);
            acc = __builtin_amdgcn_mfma_f32_16x16x32_f16(af, bf1[kk], acc, 0, 0, 0);
        }
        // prefetch GEMM2 B while the epilogue + barrier run
        #pragma unroll
        for (int kk = 0; kk < 8; ++kk)
            bf2[kk] = PW2[(wid * 8 + kk) * 64 + lane];

        const float b1v = 10.f * B1[wid * 16 + ccol];
        #pragma unroll
        for (int i = 0; i < 4; ++i)
            sf2[row0 + i][TGS_D + wid * 16 + ccol] = (f16)fmaxf(acc[i] + b1v, 0.f);
    }
    __syncthreads();

    // ---- GEMM2: out = A2 @ W2cat + tvec ----
    {
        f32x4 acc = {0.f, 0.f, 0.f, 0.f};
        const f16* abase = &sf2[ccol][(lane >> 4) * 8];
        #pragma unroll
        for (int kk = 0; kk < 8; ++kk) {
            const f16x8 af = *(const f16x8*)(abase + kk * 32);
            acc = __builtin_amdgcn_mfma_f32_16x16x32_f16(af, bf2[kk], acc, 0, 0, 0);
        }
        const float tv = tvec[wid * 16 + ccol];
        #pragma unroll
        for (int i = 0; i < 4; ++i)
            out[(base_row + row0 + i) * TGS_D + wid * 16 + ccol] = (OutT)(acc[i] + tv);
    }
}

extern "C" void kernel_launch(void* const* d_in, const int* in_sizes, int n_in,
                              void* d_out, int out_size, void* d_ws, size_t ws_size,
                              hipStream_t stream) {
    const float* NF   = (const float*)d_in[0];
    const float* EF   = (const float*)d_in[1];
    const int*   SRC  = (const int*)  d_in[2];
    const float* TS   = (const float*)d_in[3];
    const int*   NBR1 = (const int*)  d_in[4];
    const int*   EI1  = (const int*)  d_in[5];
    const float* ET1  = (const float*)d_in[6];
    const int*   NBR2 = (const int*)  d_in[7];
    const int*   EI2  = (const int*)  d_in[8];
    const float* ET2  = (const float*)d_in[9];
    const float* TW   = (const float*)d_in[10];
    const float* TB   = (const float*)d_in[11];
    const float* W1   = (const float*)d_in[12];  // [2,276,128]
    const float* B1   = (const float*)d_in[13];  // [2,128]
    const float* W2   = (const float*)d_in[14];  // [2,384,128]
    const float* B2   = (const float*)d_in[15];  // [2,128]

    // workspace layout (16B-aligned offsets)
    f16*   emb1 = (f16*)d_ws;                                // 40960*128*2 = 10,485,760 B
    char*  wsb  = (char*)d_ws + 40960 * TGS_D * 2;
    f16x8* PW1  = (f16x8*)wsb;                               // 2*8*9*64*16  = 147,456 B
    f16x8* PW2  = (f16x8*)(wsb + 147456);                    // 2*8*8*64*16  = 131,072 B
    float* tvec = (float*)(wsb + 147456 + 131072);           // 2*128*4      = 1,024 B

    tgs_setup<<<274, 128, 0, stream>>>(W1, W2, TB, B2, PW1, PW2, tvec);

    const int n1 = 4096 * TGS_K;   // 40960 level-1 rows
    const int n2 = 4096;

    // Level 1 (layer-0 weights) -> emb1 (f16)
    tgs_agg_kernel<1, f16><<<n1 / RPB, 512, 0, stream>>>(
        NF, EF, NBR1, TS, NBR2, EI2, ET2, (const f16*)nullptr,
        TW, TB, PW1, B1, PW2, tvec, emb1);

    // Level 2 (layer-1 weights) -> d_out (f32)
    tgs_agg_kernel<2, float><<<n2 / RPB, 512, 0, stream>>>(
        NF, EF, SRC, TS, nullptr, EI1, ET1, emb1,
        TW, TB,
        PW1 + 8 * 9 * 64, B1 + TGS_D,
        PW2 + 8 * 8 * 64, tvec + TGS_D,
        (float*)d_out);
}